// Round 1
// baseline (1282.094 us; speedup 1.0000x reference)
//
#include <hip/hip_runtime.h>
#include <cstdint>
#include <cstddef>

// Problem constants: B=8, N=256, H=128
// ws layout (floats):
//   Vx   @ 0        (2048*128)
//   Vnx  @ 262144
//   Ux   @ 524288
//   agg  @ 786432
//   esum @ 1048576 (128), esumsq @ 1048704 (128)
//   esc  @ 1048832 (128), esh    @ 1048960 (128)

typedef float  f4v  __attribute__((ext_vector_type(4)));
typedef short  s8v  __attribute__((ext_vector_type(8)));

__device__ __forceinline__ unsigned short f2bf(float x) {
    unsigned u = __builtin_bit_cast(unsigned, x);
    u = (u + 0x7FFFu + ((u >> 16) & 1u)) >> 16;
    return (unsigned short)u;
}

__device__ __forceinline__ float sigmoid_f(float v) {
    float e = exp2f(-1.44269504088896f * v);     // v_exp_f32
    return __builtin_amdgcn_rcpf(1.0f + e);      // v_rcp_f32, ~1ulp: fine vs 0.165 thr
}

// ---------------- K0: Vx = x@Ve^T+b, Vnx = x@Vn^T+b, Ux = x@Un^T+b ----------------
__global__ __launch_bounds__(256) void k0_proj(
    const float* __restrict__ x,
    const float* __restrict__ Ve_w, const float* __restrict__ Ve_b,
    const float* __restrict__ Vn_w, const float* __restrict__ Vn_b,
    const float* __restrict__ Un_w, const float* __restrict__ Un_b,
    float* __restrict__ ws)
{
    int bid = blockIdx.x;              // 0..767 : m = bid>>8, 8 rows per block
    int m = bid >> 8;
    int rbase = (bid & 255) * 8;
    int tid = threadIdx.x;
    int h = tid & 127;
    int lr = tid >> 7;                 // 0..1

    const float* W; const float* bb; float* out;
    if (m == 0)      { W = Ve_w; bb = Ve_b; out = ws; }
    else if (m == 1) { W = Vn_w; bb = Vn_b; out = ws + 262144; }
    else             { W = Un_w; bb = Un_b; out = ws + 524288; }

    __shared__ __align__(16) float xs[8][128];
    for (int idx = tid; idx < 1024; idx += 256)
        xs[idx >> 7][idx & 127] = x[(rbase + (idx >> 7)) * 128 + (idx & 127)];

    if (bid == 0) ws[1048576 + tid] = 0.0f;   // zero esum/esumsq (256 floats)
    __syncthreads();

    float acc[4] = {0.f, 0.f, 0.f, 0.f};
    float bv = bb[h];
    const float4* Wr = (const float4*)(W + h * 128);
    for (int k4 = 0; k4 < 32; ++k4) {
        float4 w4 = Wr[k4];
        int k = k4 * 4;
        #pragma unroll
        for (int q = 0; q < 4; ++q) {
            int rl = lr * 4 + q;
            acc[q] += w4.x * xs[rl][k] + w4.y * xs[rl][k + 1]
                    + w4.z * xs[rl][k + 2] + w4.w * xs[rl][k + 3];
        }
    }
    #pragma unroll
    for (int q = 0; q < 4; ++q)
        out[(rbase + lr * 4 + q) * 128 + h] = acc[q] + bv;
}

// ---------------- K1: pass A over e — stats + agg (e_new NOT stored) ----------------
__global__ __launch_bounds__(256, 4) void k1_stats(
    const float* __restrict__ e,
    const float* __restrict__ Ue_w, const float* __restrict__ Ue_b,
    float* __restrict__ ws)
{
    const float* Vx  = ws;
    const float* Vnx = ws + 262144;
    float* agg    = ws + 786432;
    float* esum   = ws + 1048576;
    float* esumsq = ws + 1048704;

    int bid = blockIdx.x;              // b*256 + i
    int b = bid >> 8;
    int tid = threadIdx.x;
    int wave = tid >> 6;
    int lane = tid & 63;
    int col  = lane & 15;
    int quad = lane >> 4;

    __shared__ __align__(16) unsigned short Wl[128 * 136];  // bf16 W[h][k], pad->2-way free
    __shared__ __align__(16) unsigned short Al[16 * 136];   // bf16 e-tile
    __shared__ float addi[128];                             // Ue_b + Vx[b,i,:]

    for (int t = tid * 8; t < 16384; t += 2048) {
        int row = t >> 7, c = t & 127;
        const float4* src = (const float4*)(Ue_w + t);
        float4 v0 = src[0], v1 = src[1];
        s8v pk;
        pk[0] = (short)f2bf(v0.x); pk[1] = (short)f2bf(v0.y);
        pk[2] = (short)f2bf(v0.z); pk[3] = (short)f2bf(v0.w);
        pk[4] = (short)f2bf(v1.x); pk[5] = (short)f2bf(v1.y);
        pk[6] = (short)f2bf(v1.z); pk[7] = (short)f2bf(v1.w);
        *(s8v*)(&Wl[row * 136 + c]) = pk;
    }
    if (tid < 128) addi[tid] = Ue_b[tid] + Vx[bid * 128 + tid];
    __syncthreads();

    float sum0 = 0.f, sum1 = 0.f, ss0 = 0.f, ss1 = 0.f, ag0 = 0.f, ag1 = 0.f;
    int h0 = wave * 32 + col;
    int h1 = h0 + 16;

    const int arow = tid >> 4, akb = (tid & 15) * 8;
    const float* eblk = e + (size_t)bid * 32768;

    for (int jt = 0; jt < 16; ++jt) {
        int jbase = jt * 16;
        {   // stage 16x128 e rows -> bf16 LDS
            const float4* src = (const float4*)(eblk + (jbase + arow) * 128 + akb);
            float4 v0 = src[0], v1 = src[1];
            s8v pk;
            pk[0] = (short)f2bf(v0.x); pk[1] = (short)f2bf(v0.y);
            pk[2] = (short)f2bf(v0.z); pk[3] = (short)f2bf(v0.w);
            pk[4] = (short)f2bf(v1.x); pk[5] = (short)f2bf(v1.y);
            pk[6] = (short)f2bf(v1.z); pk[7] = (short)f2bf(v1.w);
            *(s8v*)(&Al[arow * 136 + akb]) = pk;
        }
        __syncthreads();

        f4v acc0 = {0.f, 0.f, 0.f, 0.f}, acc1 = {0.f, 0.f, 0.f, 0.f};
        #pragma unroll
        for (int kk = 0; kk < 4; ++kk) {
            int ko = kk * 32 + quad * 8;
            s8v a  = *(const s8v*)(&Al[col * 136 + ko]);
            s8v b0 = *(const s8v*)(&Wl[h0 * 136 + ko]);
            s8v b1 = *(const s8v*)(&Wl[h1 * 136 + ko]);
            acc0 = __builtin_amdgcn_mfma_f32_16x16x32_bf16(a, b0, acc0, 0, 0, 0);
            acc1 = __builtin_amdgcn_mfma_f32_16x16x32_bf16(a, b1, acc1, 0, 0, 0);
        }
        float ai0 = addi[h0], ai1 = addi[h1];
        #pragma unroll
        for (int r = 0; r < 4; ++r) {
            int j = jbase + quad * 4 + r;
            const float* vxr = Vx  + ((b << 8) + j) * 128;
            const float* vnr = Vnx + ((b << 8) + j) * 128;
            float v0 = acc0[r] + ai0 + vxr[h0];
            float v1 = acc1[r] + ai1 + vxr[h1];
            sum0 += v0; ss0 += v0 * v0;
            sum1 += v1; ss1 += v1 * v1;
            ag0 += sigmoid_f(v0) * vnr[h0];
            ag1 += sigmoid_f(v1) * vnr[h1];
        }
        __syncthreads();
    }

    // quads partition j: reduce across quad bits (lanes 16,32)
    sum0 += __shfl_xor(sum0, 16); sum0 += __shfl_xor(sum0, 32);
    sum1 += __shfl_xor(sum1, 16); sum1 += __shfl_xor(sum1, 32);
    ss0  += __shfl_xor(ss0, 16);  ss0  += __shfl_xor(ss0, 32);
    ss1  += __shfl_xor(ss1, 16);  ss1  += __shfl_xor(ss1, 32);
    ag0  += __shfl_xor(ag0, 16);  ag0  += __shfl_xor(ag0, 32);
    ag1  += __shfl_xor(ag1, 16);  ag1  += __shfl_xor(ag1, 32);

    if (lane < 16) {   // col==lane; each wave owns disjoint h
        atomicAdd(&esum[h0], sum0);
        atomicAdd(&esumsq[h0], ss0);
        atomicAdd(&esum[h1], sum1);
        atomicAdd(&esumsq[h1], ss1);
        agg[bid * 128 + h0] = ag0;
        agg[bid * 128 + h1] = ag1;
    }
}

// ---------------- K1.5: finalize BN params + x-side output ----------------
__global__ __launch_bounds__(256) void k15_finalize(
    const float* __restrict__ x,
    const float* __restrict__ bne_w, const float* __restrict__ bne_b,
    const float* __restrict__ bnn_w, const float* __restrict__ bnn_b,
    float* __restrict__ ws, float* __restrict__ out_x)
{
    int tid = threadIdx.x;
    const float* Ux  = ws + 524288;
    const float* agg = ws + 786432;
    float* esum = ws + 1048576;  float* esumsq = ws + 1048704;
    float* esc  = ws + 1048832;  float* esh    = ws + 1048960;

    if (tid < 128) {
        float m = esum[tid] * (1.0f / 524288.0f);
        float q = esumsq[tid] * (1.0f / 524288.0f);
        float var = q - m * m;
        float rs = rsqrtf(var + 1e-5f);
        float sc = rs * bne_w[tid];
        esc[tid] = sc;
        esh[tid] = bne_b[tid] - m * sc;
    }

    int h = tid & 127, grp = tid >> 7;
    float s = 0.f, ss = 0.f;
    for (int r = grp; r < 2048; r += 2) {
        float v = Ux[r * 128 + h] + agg[r * 128 + h];
        s += v; ss += v * v;
    }
    __shared__ float sh_s[2][128], sh_q[2][128], nsc[128], nsh[128];
    sh_s[grp][h] = s; sh_q[grp][h] = ss;
    __syncthreads();
    if (tid < 128) {
        float st = sh_s[0][tid] + sh_s[1][tid];
        float qt = sh_q[0][tid] + sh_q[1][tid];
        float m = st * (1.0f / 2048.0f);
        float var = qt * (1.0f / 2048.0f) - m * m;
        float rs = rsqrtf(var + 1e-5f);
        float sc = rs * bnn_w[tid];
        nsc[tid] = sc; nsh[tid] = bnn_b[tid] - m * sc;
    }
    __syncthreads();
    float scv = nsc[h], shv = nsh[h];
    for (int r = grp; r < 2048; r += 2) {
        float v = Ux[r * 128 + h] + agg[r * 128 + h];
        float bn = v * scv + shv;
        out_x[r * 128 + h] = x[r * 128 + h] + fmaxf(bn, 0.0f);
    }
}

// ---------------- K2: pass B over e — recompute e_new, BN+ReLU+residual ----------------
__global__ __launch_bounds__(256, 3) void k2_apply(
    const float* __restrict__ e,
    const float* __restrict__ Ue_w, const float* __restrict__ Ue_b,
    const float* __restrict__ ws, float* __restrict__ out_e)
{
    const float* Vx  = ws;
    const float* esc = ws + 1048832;
    const float* esh = ws + 1048960;

    int bid = blockIdx.x;
    int b = bid >> 8;
    int tid = threadIdx.x;
    int wave = tid >> 6;
    int lane = tid & 63;
    int col  = lane & 15;
    int quad = lane >> 4;

    __shared__ __align__(16) unsigned short Wl[128 * 136];
    __shared__ __align__(16) float Af[16 * 132];   // fp32 e-tile (GEMM A + residual)
    __shared__ __align__(16) float Ot[16 * 132];   // output tile for coalesced store
    __shared__ float addi[128], escl[128], eshl[128];

    for (int t = tid * 8; t < 16384; t += 2048) {
        int row = t >> 7, c = t & 127;
        const float4* src = (const float4*)(Ue_w + t);
        float4 v0 = src[0], v1 = src[1];
        s8v pk;
        pk[0] = (short)f2bf(v0.x); pk[1] = (short)f2bf(v0.y);
        pk[2] = (short)f2bf(v0.z); pk[3] = (short)f2bf(v0.w);
        pk[4] = (short)f2bf(v1.x); pk[5] = (short)f2bf(v1.y);
        pk[6] = (short)f2bf(v1.z); pk[7] = (short)f2bf(v1.w);
        *(s8v*)(&Wl[row * 136 + c]) = pk;
    }
    if (tid < 128) {
        addi[tid] = Ue_b[tid] + Vx[bid * 128 + tid];
        escl[tid] = esc[tid];
        eshl[tid] = esh[tid];
    }
    __syncthreads();

    const int arow = tid >> 4, akb = (tid & 15) * 8;
    const float* eblk = e + (size_t)bid * 32768;
    float* oblk = out_e + (size_t)bid * 32768;
    int h0 = wave * 32 + col;
    int h1 = h0 + 16;

    for (int jt = 0; jt < 16; ++jt) {
        int jbase = jt * 16;
        {   // stage 16x128 e rows fp32
            const float4* src = (const float4*)(eblk + (jbase + arow) * 128 + akb);
            float4 v0 = src[0], v1 = src[1];
            *(float4*)(&Af[arow * 132 + akb])     = v0;
            *(float4*)(&Af[arow * 132 + akb + 4]) = v1;
        }
        __syncthreads();

        f4v acc0 = {0.f, 0.f, 0.f, 0.f}, acc1 = {0.f, 0.f, 0.f, 0.f};
        #pragma unroll
        for (int kk = 0; kk < 4; ++kk) {
            int ko = kk * 32 + quad * 8;
            const float* ap = &Af[col * 132 + ko];
            float4 p0 = *(const float4*)ap;
            float4 p1 = *(const float4*)(ap + 4);
            s8v a;
            a[0] = (short)f2bf(p0.x); a[1] = (short)f2bf(p0.y);
            a[2] = (short)f2bf(p0.z); a[3] = (short)f2bf(p0.w);
            a[4] = (short)f2bf(p1.x); a[5] = (short)f2bf(p1.y);
            a[6] = (short)f2bf(p1.z); a[7] = (short)f2bf(p1.w);
            s8v b0 = *(const s8v*)(&Wl[h0 * 136 + ko]);
            s8v b1 = *(const s8v*)(&Wl[h1 * 136 + ko]);
            acc0 = __builtin_amdgcn_mfma_f32_16x16x32_bf16(a, b0, acc0, 0, 0, 0);
            acc1 = __builtin_amdgcn_mfma_f32_16x16x32_bf16(a, b1, acc1, 0, 0, 0);
        }
        float ai0 = addi[h0], ai1 = addi[h1];
        float sc0 = escl[h0], sv0 = eshl[h0];
        float sc1 = escl[h1], sv1 = eshl[h1];
        #pragma unroll
        for (int r = 0; r < 4; ++r) {
            int jl = quad * 4 + r;
            int j = jbase + jl;
            const float* vxr = Vx + ((b << 8) + j) * 128;
            float v0 = acc0[r] + ai0 + vxr[h0];
            float v1 = acc1[r] + ai1 + vxr[h1];
            float r0 = fmaxf(v0 * sc0 + sv0, 0.0f);
            float r1 = fmaxf(v1 * sc1 + sv1, 0.0f);
            Ot[jl * 132 + h0] = Af[jl * 132 + h0] + r0;
            Ot[jl * 132 + h1] = Af[jl * 132 + h1] + r1;
        }
        __syncthreads();

        {   // coalesced store of 16x128 output tile
            float4 o0 = *(const float4*)(&Ot[arow * 132 + akb]);
            float4 o1 = *(const float4*)(&Ot[arow * 132 + akb + 4]);
            float4* dst = (float4*)(oblk + (jbase + arow) * 128 + akb);
            dst[0] = o0; dst[1] = o1;
        }
    }
}

extern "C" void kernel_launch(void* const* d_in, const int* in_sizes, int n_in,
                              void* d_out, int out_size, void* d_ws, size_t ws_size,
                              hipStream_t stream)
{
    const float* x     = (const float*)d_in[0];
    const float* e     = (const float*)d_in[1];
    const float* Ue_w  = (const float*)d_in[2];
    const float* Ue_b  = (const float*)d_in[3];
    const float* Ve_w  = (const float*)d_in[4];
    const float* Ve_b  = (const float*)d_in[5];
    const float* Un_w  = (const float*)d_in[6];
    const float* Un_b  = (const float*)d_in[7];
    const float* Vn_w  = (const float*)d_in[8];
    const float* Vn_b  = (const float*)d_in[9];
    const float* bne_w = (const float*)d_in[10];
    const float* bne_b = (const float*)d_in[11];
    const float* bnn_w = (const float*)d_in[12];
    const float* bnn_b = (const float*)d_in[13];
    float* ws    = (float*)d_ws;
    float* out_x = (float*)d_out;
    float* out_e = (float*)d_out + 262144;

    hipLaunchKernelGGL(k0_proj, dim3(768), dim3(256), 0, stream,
                       x, Ve_w, Ve_b, Vn_w, Vn_b, Un_w, Un_b, ws);
    hipLaunchKernelGGL(k1_stats, dim3(2048), dim3(256), 0, stream,
                       e, Ue_w, Ue_b, ws);
    hipLaunchKernelGGL(k15_finalize, dim3(1), dim3(256), 0, stream,
                       x, bne_w, bne_b, bnn_w, bnn_b, ws, out_x);
    hipLaunchKernelGGL(k2_apply, dim3(2048), dim3(256), 0, stream,
                       e, Ue_w, Ue_b, ws, out_e);
}

// Round 2
// 609.984 us; speedup vs baseline: 2.1018x; 2.1018x over previous
//
#include <hip/hip_runtime.h>
#include <cstdint>
#include <cstddef>

// Problem constants: B=8, N=256, H=128
// ws layout (floats):
//   Vx    @ 0        (2048*128)
//   Vnx   @ 262144
//   Ux    @ 524288
//   agg   @ 786432
//   esum  @ 1048576 (128), esumsq @ 1048704 (128)
//   nsum  @ 1048832 (128), nsumsq @ 1048960 (128)
//   esc   @ 1049088, esh @ 1049216, nsc @ 1049344, nsh @ 1049472

typedef float  f4v  __attribute__((ext_vector_type(4)));
typedef short  s8v  __attribute__((ext_vector_type(8)));

__device__ __forceinline__ unsigned short f2bf(float x) {
    unsigned u = __builtin_bit_cast(unsigned, x);
    u = (u + 0x7FFFu + ((u >> 16) & 1u)) >> 16;
    return (unsigned short)u;
}

__device__ __forceinline__ float sigmoid_f(float v) {
    float e = exp2f(-1.44269504088896f * v);     // v_exp_f32
    return __builtin_amdgcn_rcpf(1.0f + e);      // v_rcp_f32, ~1ulp: fine vs 0.165 thr
}

// ---------------- K0: Vx = x@Ve^T+b, Vnx = x@Vn^T+b, Ux = x@Un^T+b ----------------
__global__ __launch_bounds__(256) void k0_proj(
    const float* __restrict__ x,
    const float* __restrict__ Ve_w, const float* __restrict__ Ve_b,
    const float* __restrict__ Vn_w, const float* __restrict__ Vn_b,
    const float* __restrict__ Un_w, const float* __restrict__ Un_b,
    float* __restrict__ ws)
{
    int bid = blockIdx.x;              // 0..767 : m = bid>>8, 8 rows per block
    int m = bid >> 8;
    int rbase = (bid & 255) * 8;
    int tid = threadIdx.x;
    int h = tid & 127;
    int lr = tid >> 7;                 // 0..1

    const float* W; const float* bb; float* out;
    if (m == 0)      { W = Ve_w; bb = Ve_b; out = ws; }
    else if (m == 1) { W = Vn_w; bb = Vn_b; out = ws + 262144; }
    else             { W = Un_w; bb = Un_b; out = ws + 524288; }

    __shared__ __align__(16) float xs[8][128];
    for (int idx = tid; idx < 1024; idx += 256)
        xs[idx >> 7][idx & 127] = x[(rbase + (idx >> 7)) * 128 + (idx & 127)];

    if (bid == 0) {                    // zero esum/esumsq/nsum/nsumsq (512 floats)
        ws[1048576 + tid] = 0.0f;
        ws[1048576 + 256 + tid] = 0.0f;
    }
    __syncthreads();

    float acc[4] = {0.f, 0.f, 0.f, 0.f};
    float bv = bb[h];
    const float4* Wr = (const float4*)(W + h * 128);
    for (int k4 = 0; k4 < 32; ++k4) {
        float4 w4 = Wr[k4];
        int k = k4 * 4;
        #pragma unroll
        for (int q = 0; q < 4; ++q) {
            int rl = lr * 4 + q;
            acc[q] += w4.x * xs[rl][k] + w4.y * xs[rl][k + 1]
                    + w4.z * xs[rl][k + 2] + w4.w * xs[rl][k + 3];
        }
    }
    #pragma unroll
    for (int q = 0; q < 4; ++q)
        out[(rbase + lr * 4 + q) * 128 + h] = acc[q] + bv;
}

// ---------------- K1: pass A over e — stats + agg + node stats ----------------
__global__ __launch_bounds__(256, 4) void k1_stats(
    const float* __restrict__ e,
    const float* __restrict__ Ue_w, const float* __restrict__ Ue_b,
    float* __restrict__ ws)
{
    const float* Vx  = ws;
    const float* Vnx = ws + 262144;
    const float* Ux  = ws + 524288;
    float* agg    = ws + 786432;
    float* esum   = ws + 1048576;
    float* esumsq = ws + 1048704;
    float* nsum   = ws + 1048832;
    float* nsumsq = ws + 1048960;

    int bid = blockIdx.x;              // b*256 + i
    int b = bid >> 8;
    int tid = threadIdx.x;
    int wave = tid >> 6;
    int lane = tid & 63;
    int col  = lane & 15;
    int quad = lane >> 4;

    __shared__ __align__(16) unsigned short Wl[128 * 136];  // bf16 W[h][k], pad->2-way free
    __shared__ __align__(16) unsigned short Al[16 * 136];   // bf16 e-tile
    __shared__ float addi[128];                             // Ue_b + Vx[b,i,:]

    for (int t = tid * 8; t < 16384; t += 2048) {
        int row = t >> 7, c = t & 127;
        const float4* src = (const float4*)(Ue_w + t);
        float4 v0 = src[0], v1 = src[1];
        s8v pk;
        pk[0] = (short)f2bf(v0.x); pk[1] = (short)f2bf(v0.y);
        pk[2] = (short)f2bf(v0.z); pk[3] = (short)f2bf(v0.w);
        pk[4] = (short)f2bf(v1.x); pk[5] = (short)f2bf(v1.y);
        pk[6] = (short)f2bf(v1.z); pk[7] = (short)f2bf(v1.w);
        *(s8v*)(&Wl[row * 136 + c]) = pk;
    }
    if (tid < 128) addi[tid] = Ue_b[tid] + Vx[bid * 128 + tid];
    __syncthreads();

    float sum0 = 0.f, sum1 = 0.f, ss0 = 0.f, ss1 = 0.f, ag0 = 0.f, ag1 = 0.f;
    int h0 = wave * 32 + col;
    int h1 = h0 + 16;

    const int arow = tid >> 4, akb = (tid & 15) * 8;
    const float* eblk = e + (size_t)bid * 32768;

    for (int jt = 0; jt < 16; ++jt) {
        int jbase = jt * 16;
        {   // stage 16x128 e rows -> bf16 LDS
            const float4* src = (const float4*)(eblk + (jbase + arow) * 128 + akb);
            float4 v0 = src[0], v1 = src[1];
            s8v pk;
            pk[0] = (short)f2bf(v0.x); pk[1] = (short)f2bf(v0.y);
            pk[2] = (short)f2bf(v0.z); pk[3] = (short)f2bf(v0.w);
            pk[4] = (short)f2bf(v1.x); pk[5] = (short)f2bf(v1.y);
            pk[6] = (short)f2bf(v1.z); pk[7] = (short)f2bf(v1.w);
            *(s8v*)(&Al[arow * 136 + akb]) = pk;
        }
        __syncthreads();

        f4v acc0 = {0.f, 0.f, 0.f, 0.f}, acc1 = {0.f, 0.f, 0.f, 0.f};
        #pragma unroll
        for (int kk = 0; kk < 4; ++kk) {
            int ko = kk * 32 + quad * 8;
            s8v a  = *(const s8v*)(&Al[col * 136 + ko]);
            s8v b0 = *(const s8v*)(&Wl[h0 * 136 + ko]);
            s8v b1 = *(const s8v*)(&Wl[h1 * 136 + ko]);
            acc0 = __builtin_amdgcn_mfma_f32_16x16x32_bf16(a, b0, acc0, 0, 0, 0);
            acc1 = __builtin_amdgcn_mfma_f32_16x16x32_bf16(a, b1, acc1, 0, 0, 0);
        }
        float ai0 = addi[h0], ai1 = addi[h1];
        #pragma unroll
        for (int r = 0; r < 4; ++r) {
            int j = jbase + quad * 4 + r;
            const float* vxr = Vx  + ((b << 8) + j) * 128;
            const float* vnr = Vnx + ((b << 8) + j) * 128;
            float v0 = acc0[r] + ai0 + vxr[h0];
            float v1 = acc1[r] + ai1 + vxr[h1];
            sum0 += v0; ss0 += v0 * v0;
            sum1 += v1; ss1 += v1 * v1;
            ag0 += sigmoid_f(v0) * vnr[h0];
            ag1 += sigmoid_f(v1) * vnr[h1];
        }
        __syncthreads();
    }

    // quads partition j: reduce across quad bits (lanes 16,32)
    sum0 += __shfl_xor(sum0, 16); sum0 += __shfl_xor(sum0, 32);
    sum1 += __shfl_xor(sum1, 16); sum1 += __shfl_xor(sum1, 32);
    ss0  += __shfl_xor(ss0, 16);  ss0  += __shfl_xor(ss0, 32);
    ss1  += __shfl_xor(ss1, 16);  ss1  += __shfl_xor(ss1, 32);
    ag0  += __shfl_xor(ag0, 16);  ag0  += __shfl_xor(ag0, 32);
    ag1  += __shfl_xor(ag1, 16);  ag1  += __shfl_xor(ag1, 32);

    if (lane < 16) {   // col==lane; each wave owns disjoint h
        atomicAdd(&esum[h0], sum0);
        atomicAdd(&esumsq[h0], ss0);
        atomicAdd(&esum[h1], sum1);
        atomicAdd(&esumsq[h1], ss1);
        agg[bid * 128 + h0] = ag0;
        agg[bid * 128 + h1] = ag1;
        // node-side: x_new row bid is final here -> accumulate BN stats
        float v0 = Ux[bid * 128 + h0] + ag0;
        float v1 = Ux[bid * 128 + h1] + ag1;
        atomicAdd(&nsum[h0], v0);
        atomicAdd(&nsumsq[h0], v0 * v0);
        atomicAdd(&nsum[h1], v1);
        atomicAdd(&nsumsq[h1], v1 * v1);
    }
}

// ---------------- K1.5: finalize BN scale/shift only (1 block, 128 thr) ----------------
__global__ __launch_bounds__(128) void k15_finalize(
    const float* __restrict__ bne_w, const float* __restrict__ bne_b,
    const float* __restrict__ bnn_w, const float* __restrict__ bnn_b,
    float* __restrict__ ws)
{
    int tid = threadIdx.x;
    const float* esum   = ws + 1048576;
    const float* esumsq = ws + 1048704;
    const float* nsum   = ws + 1048832;
    const float* nsumsq = ws + 1048960;
    float* esc = ws + 1049088;  float* esh = ws + 1049216;
    float* nsc = ws + 1049344;  float* nsh = ws + 1049472;

    {
        float m = esum[tid] * (1.0f / 524288.0f);
        float q = esumsq[tid] * (1.0f / 524288.0f);
        float var = q - m * m;
        float rs = rsqrtf(var + 1e-5f);
        float sc = rs * bne_w[tid];
        esc[tid] = sc;
        esh[tid] = bne_b[tid] - m * sc;
    }
    {
        float m = nsum[tid] * (1.0f / 2048.0f);
        float q = nsumsq[tid] * (1.0f / 2048.0f);
        float var = q - m * m;
        float rs = rsqrtf(var + 1e-5f);
        float sc = rs * bnn_w[tid];
        nsc[tid] = sc;
        nsh[tid] = bnn_b[tid] - m * sc;
    }
}

// ---------------- K2: pass B over e — recompute e_new, BN+ReLU+residual; + x_out ----------------
__global__ __launch_bounds__(256, 3) void k2_apply(
    const float* __restrict__ e,
    const float* __restrict__ x,
    const float* __restrict__ Ue_w, const float* __restrict__ Ue_b,
    const float* __restrict__ ws, float* __restrict__ out_x,
    float* __restrict__ out_e)
{
    const float* Vx  = ws;
    const float* Ux  = ws + 524288;
    const float* agg = ws + 786432;
    const float* esc = ws + 1049088;
    const float* esh = ws + 1049216;
    const float* nsc = ws + 1049344;
    const float* nsh = ws + 1049472;

    int bid = blockIdx.x;
    int b = bid >> 8;
    int tid = threadIdx.x;
    int wave = tid >> 6;
    int lane = tid & 63;
    int col  = lane & 15;
    int quad = lane >> 4;

    __shared__ __align__(16) unsigned short Wl[128 * 136];
    __shared__ __align__(16) float Af[16 * 132];   // fp32 e-tile (GEMM A + residual)
    __shared__ __align__(16) float Ot[16 * 132];   // output tile for coalesced store
    __shared__ float addi[128], escl[128], eshl[128];

    // x-side output: block bid owns row bid (128 elements)
    if (tid < 128) {
        float v = Ux[bid * 128 + tid] + agg[bid * 128 + tid];
        float bn = v * nsc[tid] + nsh[tid];
        out_x[bid * 128 + tid] = x[bid * 128 + tid] + fmaxf(bn, 0.0f);
    }

    for (int t = tid * 8; t < 16384; t += 2048) {
        int row = t >> 7, c = t & 127;
        const float4* src = (const float4*)(Ue_w + t);
        float4 v0 = src[0], v1 = src[1];
        s8v pk;
        pk[0] = (short)f2bf(v0.x); pk[1] = (short)f2bf(v0.y);
        pk[2] = (short)f2bf(v0.z); pk[3] = (short)f2bf(v0.w);
        pk[4] = (short)f2bf(v1.x); pk[5] = (short)f2bf(v1.y);
        pk[6] = (short)f2bf(v1.z); pk[7] = (short)f2bf(v1.w);
        *(s8v*)(&Wl[row * 136 + c]) = pk;
    }
    if (tid < 128) {
        addi[tid] = Ue_b[tid] + Vx[bid * 128 + tid];
        escl[tid] = esc[tid];
        eshl[tid] = esh[tid];
    }
    __syncthreads();

    const int arow = tid >> 4, akb = (tid & 15) * 8;
    const float* eblk = e + (size_t)bid * 32768;
    float* oblk = out_e + (size_t)bid * 32768;
    int h0 = wave * 32 + col;
    int h1 = h0 + 16;

    for (int jt = 0; jt < 16; ++jt) {
        int jbase = jt * 16;
        {   // stage 16x128 e rows fp32
            const float4* src = (const float4*)(eblk + (jbase + arow) * 128 + akb);
            float4 v0 = src[0], v1 = src[1];
            *(float4*)(&Af[arow * 132 + akb])     = v0;
            *(float4*)(&Af[arow * 132 + akb + 4]) = v1;
        }
        __syncthreads();

        f4v acc0 = {0.f, 0.f, 0.f, 0.f}, acc1 = {0.f, 0.f, 0.f, 0.f};
        #pragma unroll
        for (int kk = 0; kk < 4; ++kk) {
            int ko = kk * 32 + quad * 8;
            const float* ap = &Af[col * 132 + ko];
            float4 p0 = *(const float4*)ap;
            float4 p1 = *(const float4*)(ap + 4);
            s8v a;
            a[0] = (short)f2bf(p0.x); a[1] = (short)f2bf(p0.y);
            a[2] = (short)f2bf(p0.z); a[3] = (short)f2bf(p0.w);
            a[4] = (short)f2bf(p1.x); a[5] = (short)f2bf(p1.y);
            a[6] = (short)f2bf(p1.z); a[7] = (short)f2bf(p1.w);
            s8v b0 = *(const s8v*)(&Wl[h0 * 136 + ko]);
            s8v b1 = *(const s8v*)(&Wl[h1 * 136 + ko]);
            acc0 = __builtin_amdgcn_mfma_f32_16x16x32_bf16(a, b0, acc0, 0, 0, 0);
            acc1 = __builtin_amdgcn_mfma_f32_16x16x32_bf16(a, b1, acc1, 0, 0, 0);
        }
        float ai0 = addi[h0], ai1 = addi[h1];
        float sc0 = escl[h0], sv0 = eshl[h0];
        float sc1 = escl[h1], sv1 = eshl[h1];
        #pragma unroll
        for (int r = 0; r < 4; ++r) {
            int jl = quad * 4 + r;
            int j = jbase + jl;
            const float* vxr = Vx + ((b << 8) + j) * 128;
            float v0 = acc0[r] + ai0 + vxr[h0];
            float v1 = acc1[r] + ai1 + vxr[h1];
            float r0 = fmaxf(v0 * sc0 + sv0, 0.0f);
            float r1 = fmaxf(v1 * sc1 + sv1, 0.0f);
            Ot[jl * 132 + h0] = Af[jl * 132 + h0] + r0;
            Ot[jl * 132 + h1] = Af[jl * 132 + h1] + r1;
        }
        __syncthreads();

        {   // coalesced store of 16x128 output tile
            float4 o0 = *(const float4*)(&Ot[arow * 132 + akb]);
            float4 o1 = *(const float4*)(&Ot[arow * 132 + akb + 4]);
            float4* dst = (float4*)(oblk + (jbase + arow) * 128 + akb);
            dst[0] = o0; dst[1] = o1;
        }
    }
}

extern "C" void kernel_launch(void* const* d_in, const int* in_sizes, int n_in,
                              void* d_out, int out_size, void* d_ws, size_t ws_size,
                              hipStream_t stream)
{
    const float* x     = (const float*)d_in[0];
    const float* e     = (const float*)d_in[1];
    const float* Ue_w  = (const float*)d_in[2];
    const float* Ue_b  = (const float*)d_in[3];
    const float* Ve_w  = (const float*)d_in[4];
    const float* Ve_b  = (const float*)d_in[5];
    const float* Un_w  = (const float*)d_in[6];
    const float* Un_b  = (const float*)d_in[7];
    const float* Vn_w  = (const float*)d_in[8];
    const float* Vn_b  = (const float*)d_in[9];
    const float* bne_w = (const float*)d_in[10];
    const float* bne_b = (const float*)d_in[11];
    const float* bnn_w = (const float*)d_in[12];
    const float* bnn_b = (const float*)d_in[13];
    float* ws    = (float*)d_ws;
    float* out_x = (float*)d_out;
    float* out_e = (float*)d_out + 262144;

    hipLaunchKernelGGL(k0_proj, dim3(768), dim3(256), 0, stream,
                       x, Ve_w, Ve_b, Vn_w, Vn_b, Un_w, Un_b, ws);
    hipLaunchKernelGGL(k1_stats, dim3(2048), dim3(256), 0, stream,
                       e, Ue_w, Ue_b, ws);
    hipLaunchKernelGGL(k15_finalize, dim3(1), dim3(128), 0, stream,
                       bne_w, bne_b, bnn_w, bnn_b, ws);
    hipLaunchKernelGGL(k2_apply, dim3(2048), dim3(256), 0, stream,
                       e, x, Ue_w, Ue_b, ws, out_x, out_e);
}